// Round 3
// baseline (266.158 us; speedup 1.0000x reference)
//
#include <hip/hip_runtime.h>

// DCTFreqConv fused: 8x8 fwd DCT (fp32) -> 64ch conv1d win3 as bf16 MFMA
// (3 shifted GEMMs, weights pre-transformed to d_ws) -> 8x8 inv DCT (fp32).
//
// Prep kernel: conv_w (64,64,3) f32 -> Wt[w][o][i] bf16 in d_ws (24576 B).
// Main kernel: 1 WG = (bz, by, 4 bx blocks), 256 threads, wave = 1 sample.
// LDS: Ct[4][66][72] bf16 only = 38016 B -> 4 WG/CU.
//   Phase B: thread (c,blk) fwd-DCTs its 8x8 block, stores Ct[t][i] (t=freq).
//   Phase C: wave w: A=Ct rows (t+shift), B=Wt cols (o) from GLOBAL, D=[t][o];
//            writes Y[o][t] bf16 over own sample's Ct (b64 stores).
//   Phase D: thread (o=c,blk) reads Y row (8x ds_read_b128), +bias, inv DCT,
//            coalesced float4 stores.

#define THREADS 256
#define HW 256
#define CH 64
#define CT_ROW 72                    // shorts; 144 B, 16B-aligned rows
#define CT_SAMPLE (66 * CT_ROW)      // rows 64,65 = zero pad for t+2 shift
#define LDS_BYTES (4 * CT_SAMPLE * 2)

typedef __attribute__((ext_vector_type(8))) short short8b;
typedef __attribute__((ext_vector_type(4))) float f32x4;
typedef __attribute__((ext_vector_type(4))) unsigned short us4;
typedef __attribute__((ext_vector_type(8))) unsigned short us8;

__device__ inline unsigned short f2bf(float f) {
    unsigned u = __builtin_bit_cast(unsigned, f);
    u += 0x7FFFu + ((u >> 16) & 1u);
    return (unsigned short)(u >> 16);
}
__device__ inline float bf2f(unsigned short h) {
    unsigned u = ((unsigned)h) << 16;
    return __builtin_bit_cast(float, u);
}

__device__ __constant__ static const float D8[8][8] = {
  { 0.3535533906f, 0.3535533906f, 0.3535533906f, 0.3535533906f, 0.3535533906f, 0.3535533906f, 0.3535533906f, 0.3535533906f },
  { 0.4903926402f, 0.4157348062f, 0.2777851165f, 0.0975451610f,-0.0975451610f,-0.2777851165f,-0.4157348062f,-0.4903926402f },
  { 0.4619397663f, 0.1913417162f,-0.1913417162f,-0.4619397663f,-0.4619397663f,-0.1913417162f, 0.1913417162f, 0.4619397663f },
  { 0.4157348062f,-0.0975451610f,-0.4903926402f,-0.2777851165f, 0.2777851165f, 0.4903926402f, 0.0975451610f,-0.4157348062f },
  { 0.3535533906f,-0.3535533906f,-0.3535533906f, 0.3535533906f, 0.3535533906f,-0.3535533906f,-0.3535533906f, 0.3535533906f },
  { 0.2777851165f,-0.4903926402f, 0.0975451610f, 0.4157348062f,-0.4157348062f,-0.0975451610f, 0.4903926402f,-0.2777851165f },
  { 0.1913417162f,-0.4619397663f, 0.4619397663f,-0.1913417162f,-0.1913417162f, 0.4619397663f,-0.4619397663f, 0.1913417162f },
  { 0.0975451610f,-0.2777851165f, 0.4157348062f,-0.4903926402f, 0.4903926402f,-0.4157348062f, 0.2777851165f,-0.0975451610f },
};

// --- prep: Wt[w][o][i] bf16 <- conv_w[o*192 + i*3 + w] ---
__global__ __launch_bounds__(256)
void wt_prep_kernel(const float* __restrict__ conv_w, unsigned short* __restrict__ wt) {
    int j = blockIdx.x * 256 + threadIdx.x;           // 0 .. 12287
    int w = j >> 12;                                   // /4096
    int rem = j & 4095;
    int o = rem >> 6;
    int i = rem & 63;
    wt[j] = f2bf(conv_w[o * 192 + i * 3 + w]);
}

__global__ __launch_bounds__(THREADS, 4)
void dct_freq_conv_kernel(const float* __restrict__ x,
                          const unsigned short* __restrict__ wt,
                          const float* __restrict__ conv_b,
                          float* __restrict__ out)
{
    extern __shared__ char smem[];
    unsigned short* Ct = (unsigned short*)smem;       // [4][66][72]

    const int tid = threadIdx.x;
    const int bz  = blockIdx.z;
    const int by  = blockIdx.y;
    const int bx0 = blockIdx.x * 4;

    const int c   = tid >> 2;   // channel (B) / out-channel (D)
    const int blk = tid & 3;    // sample index within WG

    // zero pad rows t=64,65 for each sample
    {
        int s = tid >> 6, i = tid & 63;
        Ct[s * CT_SAMPLE + 64 * CT_ROW + i] = 0;
        Ct[s * CT_SAMPLE + 65 * CT_ROW + i] = 0;
    }

    // ---- Phase B: load 8x8 block, fwd DCT, write Ct[t][i=c] ----
    {
        const float* xp = x + ((((size_t)bz * CH + c) * HW + by * 8) * HW
                               + (bx0 + blk) * 8);
        float v[8][8];
        #pragma unroll
        for (int r = 0; r < 8; ++r) {
            float4 a = *reinterpret_cast<const float4*>(xp + r * HW);
            float4 b = *reinterpret_cast<const float4*>(xp + r * HW + 4);
            v[r][0] = a.x; v[r][1] = a.y; v[r][2] = a.z; v[r][3] = a.w;
            v[r][4] = b.x; v[r][5] = b.y; v[r][6] = b.z; v[r][7] = b.w;
        }
        #pragma unroll
        for (int n = 0; n < 8; ++n) {                 // rows * D^T
            float r[8];
            #pragma unroll
            for (int l = 0; l < 8; ++l) {
                float s = 0.f;
                #pragma unroll
                for (int m = 0; m < 8; ++m) s = fmaf(v[n][m], D8[l][m], s);
                r[l] = s;
            }
            #pragma unroll
            for (int l = 0; l < 8; ++l) v[n][l] = r[l];
        }
        unsigned short* ctw = Ct + blk * CT_SAMPLE + c;
        #pragma unroll
        for (int l = 0; l < 8; ++l) {                 // D * (.)  + transposed store
            #pragma unroll
            for (int k = 0; k < 8; ++k) {
                float s = 0.f;
                #pragma unroll
                for (int n = 0; n < 8; ++n) s = fmaf(D8[k][n], v[n][l], s);
                ctw[(k * 8 + l) * CT_ROW] = f2bf(s);
            }
        }
    }

    __syncthreads();

    // ---- Phase C: conv as 3 shifted GEMMs. Wave wid owns sample wid. ----
    const int wid  = tid >> 6;
    const int lane = tid & 63;
    const int lr   = lane & 15;
    const int lq   = lane >> 4;

    f32x4 acc[4][4];                                  // [t-tile][o-tile]
    #pragma unroll
    for (int n = 0; n < 4; ++n)
        #pragma unroll
        for (int m = 0; m < 4; ++m)
            acc[n][m] = (f32x4){0.f, 0.f, 0.f, 0.f};

    unsigned short* CtP = Ct + wid * CT_SAMPLE;

    #pragma unroll
    for (int kc = 0; kc < 6; ++kc) {
        const int w  = kc >> 1;
        const int i0 = (kc & 1) * 32 + 8 * lq;
        short8b a[4], b[4];
        #pragma unroll
        for (int n = 0; n < 4; ++n)                   // A: Ct rows t+w
            a[n] = *(const short8b*)&CtP[(n * 16 + lr + w) * CT_ROW + i0];
        #pragma unroll
        for (int m = 0; m < 4; ++m)                   // B: Wt[w][o=m*16+lr][i0..]
            b[m] = *(const short8b*)&wt[(w * 64 + m * 16 + lr) * 64 + i0];
        #pragma unroll
        for (int n = 0; n < 4; ++n)
            #pragma unroll
            for (int m = 0; m < 4; ++m)
                acc[n][m] = __builtin_amdgcn_mfma_f32_16x16x32_bf16(
                    a[n], b[m], acc[n][m], 0, 0, 0);
    }

    // Y[o][t] bf16 over own sample's Ct region (wave-local; LDS order preserved)
    #pragma unroll
    for (int n = 0; n < 4; ++n) {
        const int t0 = n * 16 + 4 * lq;
        #pragma unroll
        for (int m = 0; m < 4; ++m) {
            const int o = m * 16 + lr;
            us4 pk;
            #pragma unroll
            for (int j = 0; j < 4; ++j) pk[j] = f2bf(acc[n][m][j]);
            *(us4*)&CtP[o * CT_ROW + t0] = pk;
        }
    }

    __syncthreads();

    // ---- Phase D: read Y row (o=c), +bias, inv DCT, store ----
    {
        const unsigned short* yb = Ct + blk * CT_SAMPLE + c * CT_ROW;
        const float bias = conv_b[c];
        float y[64];
        #pragma unroll
        for (int j = 0; j < 8; ++j) {
            us8 v = *(const us8*)&yb[j * 8];
            #pragma unroll
            for (int e = 0; e < 8; ++e) y[j * 8 + e] = bf2f(v[e]) + bias;
        }
        // col transform: y[n*8+l] <- sum_k D8[k][n] * y[k*8+l]
        #pragma unroll
        for (int l = 0; l < 8; ++l) {
            float r[8];
            #pragma unroll
            for (int n = 0; n < 8; ++n) {
                float s = 0.f;
                #pragma unroll
                for (int k = 0; k < 8; ++k) s = fmaf(D8[k][n], y[k * 8 + l], s);
                r[n] = s;
            }
            #pragma unroll
            for (int n = 0; n < 8; ++n) y[n * 8 + l] = r[n];
        }
        float* op = out + ((((size_t)bz * CH + c) * HW + by * 8) * HW
                           + (bx0 + blk) * 8);
        #pragma unroll
        for (int n = 0; n < 8; ++n) {
            float o8[8];
            #pragma unroll
            for (int m = 0; m < 8; ++m) {
                float s = 0.f;
                #pragma unroll
                for (int l = 0; l < 8; ++l) s = fmaf(y[n * 8 + l], D8[l][m], s);
                o8[m] = s;
            }
            *reinterpret_cast<float4*>(op + n * HW)     = make_float4(o8[0], o8[1], o8[2], o8[3]);
            *reinterpret_cast<float4*>(op + n * HW + 4) = make_float4(o8[4], o8[5], o8[6], o8[7]);
        }
    }
}

extern "C" void kernel_launch(void* const* d_in, const int* in_sizes, int n_in,
                              void* d_out, int out_size, void* d_ws, size_t ws_size,
                              hipStream_t stream) {
    const float* x  = (const float*)d_in[0];
    const float* cw = (const float*)d_in[1];
    const float* cb = (const float*)d_in[2];
    float* o        = (float*)d_out;
    unsigned short* wtb = (unsigned short*)d_ws;      // 24576 B

    wt_prep_kernel<<<dim3(48), dim3(256), 0, stream>>>(cw, wtb);

    hipFuncSetAttribute(reinterpret_cast<const void*>(dct_freq_conv_kernel),
                        hipFuncAttributeMaxDynamicSharedMemorySize,
                        (int)LDS_BYTES);
    dim3 grid(8, 32, 8);  // 2048 WGs
    dct_freq_conv_kernel<<<grid, dim3(THREADS), LDS_BYTES, stream>>>(x, wtb, cb, o);
}